// Round 1
// baseline (135.422 us; speedup 1.0000x reference)
//
#include <hip/hip_runtime.h>

// MACD on [B=512, T=16384] fp32.
// Strategy: each row is split into 16 independent segments of 1024 outputs.
// Each segment is owned by ONE wave (64 lanes), which re-computes a 256-element
// warm-up window before its output range (EMA decay b_long^256 ~ 3e-9 makes the
// truncated history numerically irrelevant vs the 1.87e-2 threshold), so there
// is zero inter-block communication.
// Within a wave: chunks of 256 elements (4 per lane). Per chunk & per EMA:
//   - serial fma scan of the lane's 4 elements (zero-carry local scan)
//   - Hillis-Steele wave scan over lane aggregates with multiplier b^4
//   - per-lane carry fixup with precomputed b^(4*lane)
// Fully coalesced float4 loads/stores; no LDS.

constexpr int kB = 512;
constexpr int kT = 16384;
constexpr int kSeg = 1024;                 // output elements per wave-segment
constexpr int kWarm = 256;                 // redundant warm-up elements
constexpr int kChunk = 256;                // 64 lanes * 4 elements
constexpr int kSegsPerRow = kT / kSeg;     // 16
constexpr int kWavesPerBlock = 4;          // 256-thread blocks

struct Ema {
  float a, b, b2, b3, b4;
  float m[6];   // b^4, b^8, b^16, b^32, b^64, b^128 (wave-scan multipliers)
  float pw;     // b^(4*lane) for carry fixup
};

__device__ __forceinline__ Ema make_ema(float a, int lane) {
  Ema e;
  e.a  = a;
  e.b  = 1.0f - a;
  e.b2 = e.b * e.b;
  e.b3 = e.b2 * e.b;
  e.b4 = e.b2 * e.b2;
  float m  = e.b4;
  float pw = 1.0f;
#pragma unroll
  for (int i = 0; i < 6; ++i) {
    e.m[i] = m;
    if (lane & (1 << i)) pw *= m;   // exact product decomposition of b^(4*lane)
    m = m * m;
  }
  e.pw = pw;
  return e;
}

// One 256-element chunk of one EMA. x0..x3 are the lane's 4 consecutive inputs.
// carry = y value just before this chunk; updated to y at chunk end.
__device__ __forceinline__ void ema_chunk(const Ema& c, int lane,
                                          float x0, float x1, float x2, float x3,
                                          float& carry,
                                          float& y0, float& y1, float& y2, float& y3) {
  // zero-carry local scan of the lane's 4 elements
  float l0 = c.a * x0;
  float l1 = fmaf(c.b, l0, c.a * x1);
  float l2 = fmaf(c.b, l1, c.a * x2);
  float l3 = fmaf(c.b, l2, c.a * x3);
  // inclusive wave scan over lane aggregates, multiplier b^4
  float z = l3;
#pragma unroll
  for (int i = 0; i < 6; ++i) {
    const int d = 1 << i;
    float t = __shfl_up(z, d, 64);
    if (lane >= d) z = fmaf(c.m[i], t, z);
  }
  // exclusive value = zero-carry y at end of previous lane
  float ex = __shfl_up(z, 1, 64);
  if (lane == 0) ex = 0.0f;
  // true carry into this lane: ex + b^(4*lane) * chunk_carry
  const float cin = fmaf(c.pw, carry, ex);
  y0 = fmaf(c.b,  cin, l0);
  y1 = fmaf(c.b2, cin, l1);
  y2 = fmaf(c.b3, cin, l2);
  y3 = fmaf(c.b4, cin, l3);
  carry = __shfl(y3, 63, 64);   // y at chunk end, broadcast to all lanes
}

__global__ __launch_bounds__(kWavesPerBlock * 64, 4)
void macd_kernel(const float* __restrict__ x,
                 const int* __restrict__ p_short,
                 const int* __restrict__ p_long,
                 const int* __restrict__ p_sig,
                 float* __restrict__ out) {
  const int lane    = threadIdx.x & 63;
  const int wave    = threadIdx.x >> 6;
  const int wave_id = blockIdx.x * kWavesPerBlock + wave;
  const int row     = wave_id / kSegsPerRow;
  const int seg     = wave_id % kSegsPerRow;
  const int s       = seg * kSeg;

  const Ema cs = make_ema(2.0f / (float)(p_short[0] + 1), lane);
  const Ema cl = make_ema(2.0f / (float)(p_long[0]  + 1), lane);
  const Ema cg = make_ema(2.0f / (float)(p_sig[0]   + 1), lane);

  const int p0      = (seg == 0) ? 0 : (s - kWarm);
  const int nwarm   = (seg == 0) ? 0 : (kWarm / kChunk);   // 0 or 1 chunks
  const int nchunks = nwarm + kSeg / kChunk;               // 4 or 5

  const int rowbase = row * kT;
  const float* xseg = x + rowbase + p0;

  // init carries: pretend the series starts at p0 (exact for seg==0; for
  // mid-row segments the error decays by b^256 over the warm-up)
  const float x_init = xseg[0];
  float c_s = x_init, c_l = x_init, c_g = 0.0f;

  float* om = out + rowbase;                // macd_line
  float* og = out + kB * kT + rowbase;      // signal_line
  float* oh = out + 2 * kB * kT + rowbase;  // hist

  for (int ch = 0; ch < nchunks; ++ch) {
    const int off = ch * kChunk + lane * 4;
    const float4 xv = *(const float4*)(xseg + off);

    float s0, s1, s2, s3, l0, l1, l2, l3;
    ema_chunk(cs, lane, xv.x, xv.y, xv.z, xv.w, c_s, s0, s1, s2, s3);
    ema_chunk(cl, lane, xv.x, xv.y, xv.z, xv.w, c_l, l0, l1, l2, l3);

    const float m0 = s0 - l0, m1 = s1 - l1, m2 = s2 - l2, m3 = s3 - l3;

    float g0, g1, g2, g3;
    ema_chunk(cg, lane, m0, m1, m2, m3, c_g, g0, g1, g2, g3);

    if (ch >= nwarm) {
      const int pos = p0 + off;   // position within row
      float4 mv; mv.x = m0; mv.y = m1; mv.z = m2; mv.w = m3;
      float4 gv; gv.x = g0; gv.y = g1; gv.z = g2; gv.w = g3;
      float4 hv; hv.x = m0 - g0; hv.y = m1 - g1; hv.z = m2 - g2; hv.w = m3 - g3;
      *(float4*)(om + pos) = mv;
      *(float4*)(og + pos) = gv;
      *(float4*)(oh + pos) = hv;
    }
  }
}

extern "C" void kernel_launch(void* const* d_in, const int* in_sizes, int n_in,
                              void* d_out, int out_size, void* d_ws, size_t ws_size,
                              hipStream_t stream) {
  const float* x  = (const float*)d_in[0];
  const int* ps   = (const int*)d_in[1];
  const int* pl   = (const int*)d_in[2];
  const int* pg   = (const int*)d_in[3];
  float* out      = (float*)d_out;

  const int total_waves = kB * kSegsPerRow;               // 8192
  const int blocks = total_waves / kWavesPerBlock;        // 2048
  macd_kernel<<<blocks, kWavesPerBlock * 64, 0, stream>>>(x, ps, pl, pg, out);
}